// Round 2
// baseline (564.552 us; speedup 1.0000x reference)
//
#include <hip/hip_runtime.h>

#define BULK 2048
#define TOWER 512
#define E8D 8
#define NROWS 16384
#define LO_SCALE 2048.0f
#define LO_INV (1.0f / 2048.0f)

typedef _Float16 f16x8 __attribute__((ext_vector_type(8)));
typedef float f32x4 __attribute__((ext_vector_type(4)));

// ---------------------------------------------------------------------------
// Weight prep: fp32 [K][N] -> transposed fp16 hi/lo [N][K], lo scaled by 2^11
// ---------------------------------------------------------------------------
__global__ void k_conv_transpose(const float* __restrict__ in, int K, int N,
                                 _Float16* __restrict__ out_hi,
                                 _Float16* __restrict__ out_lo) {
    __shared__ float tile[32][33];
    int tx = threadIdx.x & 31, ty = threadIdx.x >> 5;  // 32 x 8
    int k0 = blockIdx.x * 32, n0 = blockIdx.y * 32;
#pragma unroll
    for (int i = 0; i < 32; i += 8)
        tile[ty + i][tx] = in[(size_t)(k0 + ty + i) * N + (n0 + tx)];
    __syncthreads();
#pragma unroll
    for (int i = 0; i < 32; i += 8) {
        int n = n0 + ty + i, k = k0 + tx;
        float v = tile[tx][ty + i];
        _Float16 h = (_Float16)v;
        _Float16 l = (_Float16)((v - (float)h) * LO_SCALE);
        out_hi[(size_t)n * K + k] = h;
        out_lo[(size_t)n * K + k] = l;
    }
}

// ---------------------------------------------------------------------------
// Split-fp16 GEMM: C[M][N] = A[M][K] * B[K][N], B given transposed [N][K] hi/lo.
// A either fp32 (converted in staging) or pre-split hi/lo fp16 [M][K].
// 128x128 tile, BK=32, 4 waves, 16x16x32 f16 MFMA, 3 passes (hh, hl+lh).
// ---------------------------------------------------------------------------
template <bool A_FP32>
__global__ __launch_bounds__(256, 2) void k_gemm_split(
    const float* __restrict__ Af, const _Float16* __restrict__ Ah,
    const _Float16* __restrict__ Al, const _Float16* __restrict__ Bh,
    const _Float16* __restrict__ Bl, float* __restrict__ C, int K, int N) {
    __shared__ _Float16 lds[4][128][40];  // [Ah,Al,Bh,Bl][row][k], +8 pad
    const int t = threadIdx.x;
    const int m0 = blockIdx.x * 128, n0 = blockIdx.y * 128;
    const int wid = t >> 6, lane = t & 63;
    const int wr = wid >> 1, wc = wid & 1;
    const int lr = lane & 15, kg = lane >> 4;

    f32x4 acc1[4][4] = {};
    f32x4 acc2[4][4] = {};

    const int sr = t >> 1;        // staging row 0..127
    const int sc = (t & 1) * 16;  // 0 or 16

    for (int k0 = 0; k0 < K; k0 += 32) {
        __syncthreads();
        // ---- stage A ----
        if constexpr (A_FP32) {
            const float* src = Af + (size_t)(m0 + sr) * K + k0 + sc;
            float arr[16];
            *(float4*)&arr[0]  = *(const float4*)(src + 0);
            *(float4*)&arr[4]  = *(const float4*)(src + 4);
            *(float4*)&arr[8]  = *(const float4*)(src + 8);
            *(float4*)&arr[12] = *(const float4*)(src + 12);
            f16x8 hv0, hv1, lv0, lv1;
#pragma unroll
            for (int e = 0; e < 8; ++e) {
                float va = arr[e], vb = arr[8 + e];
                _Float16 ha = (_Float16)va, hb = (_Float16)vb;
                hv0[e] = ha;
                hv1[e] = hb;
                lv0[e] = (_Float16)((va - (float)ha) * LO_SCALE);
                lv1[e] = (_Float16)((vb - (float)hb) * LO_SCALE);
            }
            *(f16x8*)&lds[0][sr][sc]     = hv0;
            *(f16x8*)&lds[0][sr][sc + 8] = hv1;
            *(f16x8*)&lds[1][sr][sc]     = lv0;
            *(f16x8*)&lds[1][sr][sc + 8] = lv1;
        } else {
            const _Float16* sah = Ah + (size_t)(m0 + sr) * K + k0 + sc;
            const _Float16* sal = Al + (size_t)(m0 + sr) * K + k0 + sc;
            *(f16x8*)&lds[0][sr][sc]     = *(const f16x8*)(sah);
            *(f16x8*)&lds[0][sr][sc + 8] = *(const f16x8*)(sah + 8);
            *(f16x8*)&lds[1][sr][sc]     = *(const f16x8*)(sal);
            *(f16x8*)&lds[1][sr][sc + 8] = *(const f16x8*)(sal + 8);
        }
        // ---- stage B ----
        {
            const _Float16* sbh = Bh + (size_t)(n0 + sr) * K + k0 + sc;
            const _Float16* sbl = Bl + (size_t)(n0 + sr) * K + k0 + sc;
            *(f16x8*)&lds[2][sr][sc]     = *(const f16x8*)(sbh);
            *(f16x8*)&lds[2][sr][sc + 8] = *(const f16x8*)(sbh + 8);
            *(f16x8*)&lds[3][sr][sc]     = *(const f16x8*)(sbl);
            *(f16x8*)&lds[3][sr][sc + 8] = *(const f16x8*)(sbl + 8);
        }
        __syncthreads();

        f16x8 a_h[4], a_l[4], b_h[4], b_l[4];
#pragma unroll
        for (int m = 0; m < 4; ++m) {
            int r = wr * 64 + m * 16 + lr;
            a_h[m] = *(const f16x8*)&lds[0][r][kg * 8];
            a_l[m] = *(const f16x8*)&lds[1][r][kg * 8];
        }
#pragma unroll
        for (int n = 0; n < 4; ++n) {
            int r = wc * 64 + n * 16 + lr;
            b_h[n] = *(const f16x8*)&lds[2][r][kg * 8];
            b_l[n] = *(const f16x8*)&lds[3][r][kg * 8];
        }
#pragma unroll
        for (int m = 0; m < 4; ++m)
#pragma unroll
            for (int n = 0; n < 4; ++n) {
                acc1[m][n] = __builtin_amdgcn_mfma_f32_16x16x32_f16(
                    a_h[m], b_h[n], acc1[m][n], 0, 0, 0);
                acc2[m][n] = __builtin_amdgcn_mfma_f32_16x16x32_f16(
                    a_h[m], b_l[n], acc2[m][n], 0, 0, 0);
                acc2[m][n] = __builtin_amdgcn_mfma_f32_16x16x32_f16(
                    a_l[m], b_h[n], acc2[m][n], 0, 0, 0);
            }
    }

    // epilogue: C = acc1 + acc2 * 2^-11 (lo parts were pre-scaled by 2^11)
#pragma unroll
    for (int m = 0; m < 4; ++m)
#pragma unroll
        for (int n = 0; n < 4; ++n)
#pragma unroll
            for (int i = 0; i < 4; ++i) {
                int row = m0 + wr * 64 + m * 16 + kg * 4 + i;
                int col = n0 + wc * 64 + n * 16 + lr;
                C[(size_t)row * N + col] = acc1[m][n][i] + acc2[m][n][i] * LO_INV;
            }
}

// ---------------------------------------------------------------------------
// E8 lattice quantizer (faithful to the reference, fp32 scalar per lane)
// ---------------------------------------------------------------------------
__device__ inline void nearest_d8(const float* x, float* f) {
    float s = 0.f;
#pragma unroll
    for (int j = 0; j < 8; ++j) {
        f[j] = rintf(x[j]);  // round-half-even == jnp.round
        s += f[j];
    }
    float besta = -1.f, beste = 0.f;
    int bidx = 0;
#pragma unroll
    for (int j = 0; j < 8; ++j) {
        float e = x[j] - f[j];
        float a = fabsf(e);
        if (a > besta) { besta = a; beste = e; bidx = j; }  // first max kept
    }
    if (fmodf(s, 2.0f) != 0.0f) {
        float adj = (beste >= 0.f) ? 1.f : -1.f;
#pragma unroll
        for (int j = 0; j < 8; ++j) f[j] += (j == bidx) ? adj : 0.f;
    }
}

__device__ inline void nearest_e8(const float* x, float* out) {
    float fa[8], xs[8], fb[8];
    nearest_d8(x, fa);
#pragma unroll
    for (int j = 0; j < 8; ++j) xs[j] = x[j] - 0.5f;
    nearest_d8(xs, fb);
#pragma unroll
    for (int j = 0; j < 8; ++j) fb[j] += 0.5f;
    float da = 0.f, db = 0.f;
#pragma unroll
    for (int j = 0; j < 8; ++j) {
        float ea = x[j] - fa[j], eb = x[j] - fb[j];
        da += ea * ea;
        db += eb * eb;
    }
    bool pa = (da <= db);
#pragma unroll
    for (int j = 0; j < 8; ++j) out[j] = pa ? fa[j] : fb[j];
}

__device__ inline float wred64(float v) {
#pragma unroll
    for (int off = 1; off < 64; off <<= 1) v += __shfl_xor(v, off, 64);
    return v;
}

// ---------------------------------------------------------------------------
// Per-row middle section: LN -> proj to 8 -> rmsnorm -> quantize -> decode
// to tower -> LN -> emit t2 as fp16 hi/lo. One wave per row.
// ---------------------------------------------------------------------------
__global__ __launch_bounds__(256) void k_rows(
    const float* __restrict__ pre1, const float* __restrict__ b_bt,
    const float* __restrict__ g_et, const float* __restrict__ be_et,
    const float* __restrict__ W_t8, const float* __restrict__ b_t8,
    const float* __restrict__ rms_g, const float* __restrict__ W_8t,
    const float* __restrict__ b_8t, const float* __restrict__ g_dt,
    const float* __restrict__ b_dt, _Float16* __restrict__ t2h,
    _Float16* __restrict__ t2l) {
    int wid = threadIdx.x >> 6, lane = threadIdx.x & 63;
    int row = blockIdx.x * 4 + wid;
    int cb = lane * 8;

    const float* src = pre1 + (size_t)row * TOWER + cb;
    float v[8];
    *(float4*)&v[0] = *(const float4*)(src);
    *(float4*)&v[4] = *(const float4*)(src + 4);
#pragma unroll
    for (int i = 0; i < 8; ++i) v[i] += b_bt[cb + i];

    // LN over 512 (two-pass)
    float s = 0.f;
#pragma unroll
    for (int i = 0; i < 8; ++i) s += v[i];
    s = wred64(s);
    float mu = s * (1.f / 512.f);
    float ss = 0.f;
#pragma unroll
    for (int i = 0; i < 8; ++i) { float d = v[i] - mu; ss += d * d; }
    ss = wred64(ss);
    float inv = 1.f / sqrtf(ss * (1.f / 512.f) + 1e-6f);
    float tw[8];
#pragma unroll
    for (int i = 0; i < 8; ++i)
        tw[i] = (v[i] - mu) * inv * g_et[cb + i] + be_et[cb + i];

    // project 512 -> 8
    float p[8] = {0.f, 0.f, 0.f, 0.f, 0.f, 0.f, 0.f, 0.f};
#pragma unroll
    for (int i = 0; i < 8; ++i) {
        const float* wr_ = W_t8 + (size_t)(cb + i) * 8;
#pragma unroll
        for (int j = 0; j < 8; ++j) p[j] += tw[i] * wr_[j];
    }
#pragma unroll
    for (int j = 0; j < 8; ++j) p[j] = wred64(p[j]);

    float e8[8];
    float ms = 0.f;
#pragma unroll
    for (int j = 0; j < 8; ++j) {
        e8[j] = p[j] + b_t8[j];
        ms += e8[j] * e8[j];
    }
    float rms = sqrtf(ms * (1.f / 8.f) + 1e-6f);
#pragma unroll
    for (int j = 0; j < 8; ++j) e8[j] = e8[j] / rms * rms_g[j];

    // residual E8 quantize, 8 levels (forward value of e8_q is exactly q)
    float q[8] = {0.f, 0.f, 0.f, 0.f, 0.f, 0.f, 0.f, 0.f};
    float r[8];
#pragma unroll
    for (int j = 0; j < 8; ++j) r[j] = e8[j];
#pragma unroll
    for (int lvl = 0; lvl < 8; ++lvl) {
        float ql[8];
        nearest_e8(r, ql);
#pragma unroll
        for (int j = 0; j < 8; ++j) { q[j] += ql[j]; r[j] -= ql[j]; }
    }

    // decode 8 -> 512
    float o[8];
#pragma unroll
    for (int i = 0; i < 8; ++i) {
        int c = cb + i;
        float acc = b_8t[c];
#pragma unroll
        for (int j = 0; j < 8; ++j) acc += q[j] * W_8t[(size_t)j * TOWER + c];
        o[i] = acc;
    }
    // LN over 512
    float s2 = 0.f;
#pragma unroll
    for (int i = 0; i < 8; ++i) s2 += o[i];
    s2 = wred64(s2);
    float mu2 = s2 * (1.f / 512.f);
    float ss2 = 0.f;
#pragma unroll
    for (int i = 0; i < 8; ++i) { float d = o[i] - mu2; ss2 += d * d; }
    ss2 = wred64(ss2);
    float inv2 = 1.f / sqrtf(ss2 * (1.f / 512.f) + 1e-6f);

    f16x8 hv, lv;
#pragma unroll
    for (int i = 0; i < 8; ++i) {
        int c = cb + i;
        float t2v = (o[i] - mu2) * inv2 * g_dt[c] + b_dt[c];
        _Float16 h = (_Float16)t2v;
        hv[i] = h;
        lv[i] = (_Float16)((t2v - (float)h) * LO_SCALE);
    }
    *(f16x8*)(t2h + (size_t)row * TOWER + cb) = hv;
    *(f16x8*)(t2l + (size_t)row * TOWER + cb) = lv;
}

// ---------------------------------------------------------------------------
// Final LN over 2048, in place on d_out (which holds t2 @ W_tb).
// ---------------------------------------------------------------------------
__global__ __launch_bounds__(256) void k_ln2(float* __restrict__ out,
                                             const float* __restrict__ b_tb,
                                             const float* __restrict__ g,
                                             const float* __restrict__ b) {
    __shared__ float red[4];
    int t = threadIdx.x, wid = t >> 6, lane = t & 63;
    size_t base = (size_t)blockIdx.x * BULK;
    int cb = t * 8;
    float v[8];
    *(float4*)&v[0] = *(const float4*)(out + base + cb);
    *(float4*)&v[4] = *(const float4*)(out + base + cb + 4);
#pragma unroll
    for (int i = 0; i < 8; ++i) v[i] += b_tb[cb + i];

    float s = 0.f;
#pragma unroll
    for (int i = 0; i < 8; ++i) s += v[i];
    s = wred64(s);
    if (lane == 0) red[wid] = s;
    __syncthreads();
    float tot = red[0] + red[1] + red[2] + red[3];
    float mu = tot * (1.f / 2048.f);
    __syncthreads();
    float ss = 0.f;
#pragma unroll
    for (int i = 0; i < 8; ++i) { float d = v[i] - mu; ss += d * d; }
    ss = wred64(ss);
    if (lane == 0) red[wid] = ss;
    __syncthreads();
    float vtot = red[0] + red[1] + red[2] + red[3];
    float inv = 1.f / sqrtf(vtot * (1.f / 2048.f) + 1e-6f);
#pragma unroll
    for (int i = 0; i < 8; ++i) v[i] = (v[i] - mu) * inv * g[cb + i] + b[cb + i];
    *(float4*)(out + base + cb) = *(float4*)&v[0];
    *(float4*)(out + base + cb + 4) = *(float4*)&v[4];
}

// ---------------------------------------------------------------------------
extern "C" void kernel_launch(void* const* d_in, const int* in_sizes, int n_in,
                              void* d_out, int out_size, void* d_ws,
                              size_t ws_size, hipStream_t stream) {
    const float* x     = (const float*)d_in[0];
    const float* W_bt  = (const float*)d_in[1];
    const float* b_bt  = (const float*)d_in[2];
    const float* g_et  = (const float*)d_in[3];
    const float* be_et = (const float*)d_in[4];
    const float* W_t8  = (const float*)d_in[5];
    const float* b_t8  = (const float*)d_in[6];
    const float* rms_g = (const float*)d_in[7];
    const float* W_8t  = (const float*)d_in[8];
    const float* b_8t  = (const float*)d_in[9];
    const float* g_dt  = (const float*)d_in[10];
    const float* b_dt  = (const float*)d_in[11];
    const float* W_tb  = (const float*)d_in[12];
    const float* b_tb  = (const float*)d_in[13];
    const float* g_db  = (const float*)d_in[14];
    const float* b_db  = (const float*)d_in[15];
    float* out = (float*)d_out;

    // Workspace layout (40 MB): weight splits + t2 hi/lo.
    char* w = (char*)d_ws;
    _Float16* Wbt_h = (_Float16*)w; w += (size_t)BULK * TOWER * 2;
    _Float16* Wbt_l = (_Float16*)w; w += (size_t)BULK * TOWER * 2;
    _Float16* Wtb_h = (_Float16*)w; w += (size_t)TOWER * BULK * 2;
    _Float16* Wtb_l = (_Float16*)w; w += (size_t)TOWER * BULK * 2;
    _Float16* t2h   = (_Float16*)w; w += (size_t)NROWS * TOWER * 2;
    _Float16* t2l   = (_Float16*)w; w += (size_t)NROWS * TOWER * 2;
    // pre1 (16384x512 fp32 = 32 MB) lives in d_out (128 MB), which is fully
    // overwritten by GEMM2 afterwards — stream-ordered, so no hazard.
    float* pre1 = out;

    // weight split+transpose: W_bt [2048][512] -> [512][2048], W_tb [512][2048] -> [2048][512]
    k_conv_transpose<<<dim3(BULK / 32, TOWER / 32), 256, 0, stream>>>(
        W_bt, BULK, TOWER, Wbt_h, Wbt_l);
    k_conv_transpose<<<dim3(TOWER / 32, BULK / 32), 256, 0, stream>>>(
        W_tb, TOWER, BULK, Wtb_h, Wtb_l);

    // encode GEMM: pre1 = x @ W_bt
    k_gemm_split<true><<<dim3(NROWS / 128, TOWER / 128), 256, 0, stream>>>(
        x, nullptr, nullptr, Wbt_h, Wbt_l, pre1, BULK, TOWER);

    // per-row: LN -> proj8 -> rmsnorm -> E8 RVQ -> decode -> LN -> t2 (hi/lo)
    k_rows<<<NROWS / 4, 256, 0, stream>>>(pre1, b_bt, g_et, be_et, W_t8, b_t8,
                                          rms_g, W_8t, b_8t, g_dt, b_dt, t2h,
                                          t2l);

    // decode GEMM: d_out = t2 @ W_tb (pre-LN)
    k_gemm_split<false><<<dim3(NROWS / 128, BULK / 128), 256, 0, stream>>>(
        nullptr, t2h, t2l, Wtb_h, Wtb_l, out, TOWER, BULK);

    // final LN in place
    k_ln2<<<NROWS, 256, 0, stream>>>(out, b_tb, g_db, b_db);
}

// Round 3
// 544.964 us; speedup vs baseline: 1.0359x; 1.0359x over previous
//
#include <hip/hip_runtime.h>

#define BULK 2048
#define TOWER 512
#define E8D 8
#define NROWS 16384
#define LO_SCALE 2048.0f
#define LO_INV (1.0f / 2048.0f)

typedef _Float16 f16x8 __attribute__((ext_vector_type(8)));
typedef float f32x4 __attribute__((ext_vector_type(4)));

// async global->LDS, 16B per lane, dest = wave-uniform base + lane*16
#define GLOAD(g, l)                                                        \
    __builtin_amdgcn_global_load_lds(                                      \
        (const __attribute__((address_space(1))) void*)(g),                \
        (__attribute__((address_space(3))) void*)(l), 16, 0, 0)

// ---------------------------------------------------------------------------
// Weight prep: fp32 [K][N] -> transposed fp16 hi/lo [N][K], lo scaled by 2^11
// ---------------------------------------------------------------------------
__global__ void k_conv_transpose(const float* __restrict__ in, int K, int N,
                                 _Float16* __restrict__ out_hi,
                                 _Float16* __restrict__ out_lo) {
    __shared__ float tile[32][33];
    int tx = threadIdx.x & 31, ty = threadIdx.x >> 5;  // 32 x 8
    int k0 = blockIdx.x * 32, n0 = blockIdx.y * 32;
#pragma unroll
    for (int i = 0; i < 32; i += 8)
        tile[ty + i][tx] = in[(size_t)(k0 + ty + i) * N + (n0 + tx)];
    __syncthreads();
#pragma unroll
    for (int i = 0; i < 32; i += 8) {
        int n = n0 + ty + i, k = k0 + tx;
        float v = tile[tx][ty + i];
        _Float16 h = (_Float16)v;
        _Float16 l = (_Float16)((v - (float)h) * LO_SCALE);
        out_hi[(size_t)n * K + k] = h;
        out_lo[(size_t)n * K + k] = l;
    }
}

// ---------------------------------------------------------------------------
// Split-fp16 GEMM, double-buffered single-barrier K-loop.
// C[M][N] = A[M][K] * B[K][N], B transposed [N][K] hi/lo fp16.
// A_FP32: A fp32, reg-staged + converted in kernel; else A pre-split hi/lo,
// staged via global_load_lds like B. 128x128 tile, BK=32, 4 waves.
// LDS ops: 0=Ah 1=Al 2=Bh 3=Bl, linear [128][32] halves (64B rows).
// ---------------------------------------------------------------------------
template <bool A_FP32>
__global__ __launch_bounds__(256, 2) void k_gemm_split(
    const float* __restrict__ Af, const _Float16* __restrict__ Ah,
    const _Float16* __restrict__ Al, const _Float16* __restrict__ Bh,
    const _Float16* __restrict__ Bl, float* __restrict__ C, int K, int N) {
    __shared__ _Float16 lds[2][4][128][32];  // 64 KB
    const int t = threadIdx.x;
    const int m0 = blockIdx.x * 128, n0 = blockIdx.y * 128;
    const int wid = t >> 6, lane = t & 63;
    const int wr = wid >> 1, wc = wid & 1;
    const int lr = lane & 15, kg = lane >> 4;

    f32x4 acc1[4][4] = {};
    f32x4 acc2[4][4] = {};

    // ---- staging geometry ----
    // A (fp32 path): thread t loads 16 floats at row sr, halves [sc, sc+16)
    const int sr = t >> 1, sc = (t & 1) * 16;
    const float* aptr = A_FP32 ? (Af + (size_t)(m0 + sr) * K + sc) : nullptr;
    float areg[16];

    // B via gload (fp32 path): wave w stages chunks {2w,2w+1} of Bh and Bl.
    // chunk c = rows [16c,16c+16): lane l -> row 16c + (l>>2), halves (l&3)*8
    const int c0 = wid * 2;
    const _Float16* bhp =
        Bh + (size_t)(n0 + c0 * 16 + (lane >> 2)) * K + (lane & 3) * 8;
    const _Float16* blp =
        Bl + (size_t)(n0 + c0 * 16 + (lane >> 2)) * K + (lane & 3) * 8;

    // all-gload path: wave w owns operand w (0=Ah 1=Al 2=Bh 3=Bl), 8 chunks
    const _Float16* gop = (wid == 0) ? Ah : (wid == 1) ? Al : (wid == 2) ? Bh : Bl;
    const int r0 = ((wid < 2) ? m0 : n0) + (lane >> 2);
    const _Float16* gp = A_FP32 ? nullptr : (gop + (size_t)r0 * K + (lane & 3) * 8);

    auto loadA = [&](int k0) {
        const float* p = aptr + k0;
        *(float4*)&areg[0] = *(const float4*)(p);
        *(float4*)&areg[4] = *(const float4*)(p + 4);
        *(float4*)&areg[8] = *(const float4*)(p + 8);
        *(float4*)&areg[12] = *(const float4*)(p + 12);
    };
    auto stageB = [&](int k0, int bb) {
        GLOAD(bhp + k0, &lds[bb][2][c0 * 16][0]);
        GLOAD(bhp + k0 + (size_t)16 * K, &lds[bb][2][c0 * 16 + 16][0]);
        GLOAD(blp + k0, &lds[bb][3][c0 * 16][0]);
        GLOAD(blp + k0 + (size_t)16 * K, &lds[bb][3][c0 * 16 + 16][0]);
    };
    auto writeA = [&](int bb) {
        f16x8 hv0, hv1, lv0, lv1;
#pragma unroll
        for (int e = 0; e < 8; ++e) {
            float va = areg[e], vb = areg[8 + e];
            _Float16 ha = (_Float16)va, hb = (_Float16)vb;
            hv0[e] = ha;
            hv1[e] = hb;
            lv0[e] = (_Float16)((va - (float)ha) * LO_SCALE);
            lv1[e] = (_Float16)((vb - (float)hb) * LO_SCALE);
        }
        *(f16x8*)&lds[bb][0][sr][sc] = hv0;
        *(f16x8*)&lds[bb][0][sr][sc + 8] = hv1;
        *(f16x8*)&lds[bb][1][sr][sc] = lv0;
        *(f16x8*)&lds[bb][1][sr][sc + 8] = lv1;
    };
    auto stageAll = [&](int k0, int bb) {
#pragma unroll
        for (int j = 0; j < 8; ++j)
            GLOAD(gp + k0 + (size_t)(j * 16) * K, &lds[bb][wid][j * 16][0]);
    };

    // ---- prologue: stage tile 0 into buf 0 ----
    if constexpr (A_FP32) {
        loadA(0);
        stageB(0, 0);
        writeA(0);
    } else {
        stageAll(0, 0);
    }
    __syncthreads();

    const int nk = K / 32;
    for (int kt = 0; kt < nk; ++kt) {
        const int b = kt & 1;
        // issue next tile's loads before computing (overlap under MFMAs)
        if (kt + 1 < nk) {
            if constexpr (A_FP32) {
                loadA((kt + 1) * 32);
                stageB((kt + 1) * 32, b ^ 1);
            } else {
                stageAll((kt + 1) * 32, b ^ 1);
            }
        }

        f16x8 a_h[4], a_l[4], b_h[4], b_l[4];
#pragma unroll
        for (int m = 0; m < 4; ++m) {
            int r = wr * 64 + m * 16 + lr;
            a_h[m] = *(const f16x8*)&lds[b][0][r][kg * 8];
            a_l[m] = *(const f16x8*)&lds[b][1][r][kg * 8];
        }
#pragma unroll
        for (int n = 0; n < 4; ++n) {
            int r = wc * 64 + n * 16 + lr;
            b_h[n] = *(const f16x8*)&lds[b][2][r][kg * 8];
            b_l[n] = *(const f16x8*)&lds[b][3][r][kg * 8];
        }
#pragma unroll
        for (int m = 0; m < 4; ++m)
#pragma unroll
            for (int n = 0; n < 4; ++n) {
                acc1[m][n] = __builtin_amdgcn_mfma_f32_16x16x32_f16(
                    a_h[m], b_h[n], acc1[m][n], 0, 0, 0);
                acc2[m][n] = __builtin_amdgcn_mfma_f32_16x16x32_f16(
                    a_h[m], b_l[n], acc2[m][n], 0, 0, 0);
                acc2[m][n] = __builtin_amdgcn_mfma_f32_16x16x32_f16(
                    a_l[m], b_h[n], acc2[m][n], 0, 0, 0);
            }

        // A conversion after MFMAs: loads have landed, VALU overlaps
        // other waves' MFMA; writes target buf b^1 (nobody reads it now).
        if constexpr (A_FP32) {
            if (kt + 1 < nk) writeA(b ^ 1);
        }
        __syncthreads();  // drains vmcnt(0)+lgkmcnt(0): next buf ready
    }

    // epilogue: C = acc1 + acc2 * 2^-11
#pragma unroll
    for (int m = 0; m < 4; ++m)
#pragma unroll
        for (int n = 0; n < 4; ++n)
#pragma unroll
            for (int i = 0; i < 4; ++i) {
                int row = m0 + wr * 64 + m * 16 + kg * 4 + i;
                int col = n0 + wc * 64 + n * 16 + lr;
                C[(size_t)row * N + col] = acc1[m][n][i] + acc2[m][n][i] * LO_INV;
            }
}

// ---------------------------------------------------------------------------
// E8 lattice quantizer (faithful to the reference, fp32 scalar per lane)
// ---------------------------------------------------------------------------
__device__ inline void nearest_d8(const float* x, float* f) {
    float s = 0.f;
#pragma unroll
    for (int j = 0; j < 8; ++j) {
        f[j] = rintf(x[j]);  // round-half-even == jnp.round
        s += f[j];
    }
    float besta = -1.f, beste = 0.f;
    int bidx = 0;
#pragma unroll
    for (int j = 0; j < 8; ++j) {
        float e = x[j] - f[j];
        float a = fabsf(e);
        if (a > besta) { besta = a; beste = e; bidx = j; }  // first max kept
    }
    if (fmodf(s, 2.0f) != 0.0f) {
        float adj = (beste >= 0.f) ? 1.f : -1.f;
#pragma unroll
        for (int j = 0; j < 8; ++j) f[j] += (j == bidx) ? adj : 0.f;
    }
}

__device__ inline void nearest_e8(const float* x, float* out) {
    float fa[8], xs[8], fb[8];
    nearest_d8(x, fa);
#pragma unroll
    for (int j = 0; j < 8; ++j) xs[j] = x[j] - 0.5f;
    nearest_d8(xs, fb);
#pragma unroll
    for (int j = 0; j < 8; ++j) fb[j] += 0.5f;
    float da = 0.f, db = 0.f;
#pragma unroll
    for (int j = 0; j < 8; ++j) {
        float ea = x[j] - fa[j], eb = x[j] - fb[j];
        da += ea * ea;
        db += eb * eb;
    }
    bool pa = (da <= db);
#pragma unroll
    for (int j = 0; j < 8; ++j) out[j] = pa ? fa[j] : fb[j];
}

__device__ inline float wred64(float v) {
#pragma unroll
    for (int off = 1; off < 64; off <<= 1) v += __shfl_xor(v, off, 64);
    return v;
}

// ---------------------------------------------------------------------------
// Per-row middle section: LN -> proj to 8 -> rmsnorm -> quantize -> decode
// to tower -> LN -> emit t2 as fp16 hi/lo. One wave per row.
// ---------------------------------------------------------------------------
__global__ __launch_bounds__(256) void k_rows(
    const float* __restrict__ pre1, const float* __restrict__ b_bt,
    const float* __restrict__ g_et, const float* __restrict__ be_et,
    const float* __restrict__ W_t8, const float* __restrict__ b_t8,
    const float* __restrict__ rms_g, const float* __restrict__ W_8t,
    const float* __restrict__ b_8t, const float* __restrict__ g_dt,
    const float* __restrict__ b_dt, _Float16* __restrict__ t2h,
    _Float16* __restrict__ t2l) {
    int wid = threadIdx.x >> 6, lane = threadIdx.x & 63;
    int row = blockIdx.x * 4 + wid;
    int cb = lane * 8;

    const float* src = pre1 + (size_t)row * TOWER + cb;
    float v[8];
    *(float4*)&v[0] = *(const float4*)(src);
    *(float4*)&v[4] = *(const float4*)(src + 4);
#pragma unroll
    for (int i = 0; i < 8; ++i) v[i] += b_bt[cb + i];

    // LN over 512 (two-pass)
    float s = 0.f;
#pragma unroll
    for (int i = 0; i < 8; ++i) s += v[i];
    s = wred64(s);
    float mu = s * (1.f / 512.f);
    float ss = 0.f;
#pragma unroll
    for (int i = 0; i < 8; ++i) { float d = v[i] - mu; ss += d * d; }
    ss = wred64(ss);
    float inv = 1.f / sqrtf(ss * (1.f / 512.f) + 1e-6f);
    float tw[8];
#pragma unroll
    for (int i = 0; i < 8; ++i)
        tw[i] = (v[i] - mu) * inv * g_et[cb + i] + be_et[cb + i];

    // project 512 -> 8
    float p[8] = {0.f, 0.f, 0.f, 0.f, 0.f, 0.f, 0.f, 0.f};
#pragma unroll
    for (int i = 0; i < 8; ++i) {
        const float* wr_ = W_t8 + (size_t)(cb + i) * 8;
#pragma unroll
        for (int j = 0; j < 8; ++j) p[j] += tw[i] * wr_[j];
    }
#pragma unroll
    for (int j = 0; j < 8; ++j) p[j] = wred64(p[j]);

    float e8[8];
    float ms = 0.f;
#pragma unroll
    for (int j = 0; j < 8; ++j) {
        e8[j] = p[j] + b_t8[j];
        ms += e8[j] * e8[j];
    }
    float rms = sqrtf(ms * (1.f / 8.f) + 1e-6f);
#pragma unroll
    for (int j = 0; j < 8; ++j) e8[j] = e8[j] / rms * rms_g[j];

    // residual E8 quantize, 8 levels (forward value of e8_q is exactly q)
    float q[8] = {0.f, 0.f, 0.f, 0.f, 0.f, 0.f, 0.f, 0.f};
    float r[8];
#pragma unroll
    for (int j = 0; j < 8; ++j) r[j] = e8[j];
#pragma unroll
    for (int lvl = 0; lvl < 8; ++lvl) {
        float ql[8];
        nearest_e8(r, ql);
#pragma unroll
        for (int j = 0; j < 8; ++j) { q[j] += ql[j]; r[j] -= ql[j]; }
    }

    // decode 8 -> 512
    float o[8];
#pragma unroll
    for (int i = 0; i < 8; ++i) {
        int c = cb + i;
        float acc = b_8t[c];
#pragma unroll
        for (int j = 0; j < 8; ++j) acc += q[j] * W_8t[(size_t)j * TOWER + c];
        o[i] = acc;
    }
    // LN over 512
    float s2 = 0.f;
#pragma unroll
    for (int i = 0; i < 8; ++i) s2 += o[i];
    s2 = wred64(s2);
    float mu2 = s2 * (1.f / 512.f);
    float ss2 = 0.f;
#pragma unroll
    for (int i = 0; i < 8; ++i) { float d = o[i] - mu2; ss2 += d * d; }
    ss2 = wred64(ss2);
    float inv2 = 1.f / sqrtf(ss2 * (1.f / 512.f) + 1e-6f);

    f16x8 hv, lv;
#pragma unroll
    for (int i = 0; i < 8; ++i) {
        int c = cb + i;
        float t2v = (o[i] - mu2) * inv2 * g_dt[c] + b_dt[c];
        _Float16 h = (_Float16)t2v;
        hv[i] = h;
        lv[i] = (_Float16)((t2v - (float)h) * LO_SCALE);
    }
    *(f16x8*)(t2h + (size_t)row * TOWER + cb) = hv;
    *(f16x8*)(t2l + (size_t)row * TOWER + cb) = lv;
}

// ---------------------------------------------------------------------------
// Final LN over 2048, in place on d_out (which holds t2 @ W_tb).
// ---------------------------------------------------------------------------
__global__ __launch_bounds__(256) void k_ln2(float* __restrict__ out,
                                             const float* __restrict__ b_tb,
                                             const float* __restrict__ g,
                                             const float* __restrict__ b) {
    __shared__ float red[4];
    int t = threadIdx.x, wid = t >> 6, lane = t & 63;
    size_t base = (size_t)blockIdx.x * BULK;
    int cb = t * 8;
    float v[8];
    *(float4*)&v[0] = *(const float4*)(out + base + cb);
    *(float4*)&v[4] = *(const float4*)(out + base + cb + 4);
#pragma unroll
    for (int i = 0; i < 8; ++i) v[i] += b_tb[cb + i];

    float s = 0.f;
#pragma unroll
    for (int i = 0; i < 8; ++i) s += v[i];
    s = wred64(s);
    if (lane == 0) red[wid] = s;
    __syncthreads();
    float tot = red[0] + red[1] + red[2] + red[3];
    float mu = tot * (1.f / 2048.f);
    __syncthreads();
    float ss = 0.f;
#pragma unroll
    for (int i = 0; i < 8; ++i) { float d = v[i] - mu; ss += d * d; }
    ss = wred64(ss);
    if (lane == 0) red[wid] = ss;
    __syncthreads();
    float vtot = red[0] + red[1] + red[2] + red[3];
    float inv = 1.f / sqrtf(vtot * (1.f / 2048.f) + 1e-6f);
#pragma unroll
    for (int i = 0; i < 8; ++i) v[i] = (v[i] - mu) * inv * g[cb + i] + b[cb + i];
    *(float4*)(out + base + cb) = *(float4*)&v[0];
    *(float4*)(out + base + cb + 4) = *(float4*)&v[4];
}

// ---------------------------------------------------------------------------
extern "C" void kernel_launch(void* const* d_in, const int* in_sizes, int n_in,
                              void* d_out, int out_size, void* d_ws,
                              size_t ws_size, hipStream_t stream) {
    const float* x     = (const float*)d_in[0];
    const float* W_bt  = (const float*)d_in[1];
    const float* b_bt  = (const float*)d_in[2];
    const float* g_et  = (const float*)d_in[3];
    const float* be_et = (const float*)d_in[4];
    const float* W_t8  = (const float*)d_in[5];
    const float* b_t8  = (const float*)d_in[6];
    const float* rms_g = (const float*)d_in[7];
    const float* W_8t  = (const float*)d_in[8];
    const float* b_8t  = (const float*)d_in[9];
    const float* g_dt  = (const float*)d_in[10];
    const float* b_dt  = (const float*)d_in[11];
    const float* W_tb  = (const float*)d_in[12];
    const float* b_tb  = (const float*)d_in[13];
    const float* g_db  = (const float*)d_in[14];
    const float* b_db  = (const float*)d_in[15];
    float* out = (float*)d_out;

    // Workspace layout (40 MB): weight splits + t2 hi/lo.
    char* w = (char*)d_ws;
    _Float16* Wbt_h = (_Float16*)w; w += (size_t)BULK * TOWER * 2;
    _Float16* Wbt_l = (_Float16*)w; w += (size_t)BULK * TOWER * 2;
    _Float16* Wtb_h = (_Float16*)w; w += (size_t)TOWER * BULK * 2;
    _Float16* Wtb_l = (_Float16*)w; w += (size_t)TOWER * BULK * 2;
    _Float16* t2h   = (_Float16*)w; w += (size_t)NROWS * TOWER * 2;
    _Float16* t2l   = (_Float16*)w; w += (size_t)NROWS * TOWER * 2;
    // pre1 (16384x512 fp32 = 32 MB) lives in d_out (128 MB), fully
    // overwritten by GEMM2 later in stream order — no hazard.
    float* pre1 = out;

    // weight split+transpose
    k_conv_transpose<<<dim3(BULK / 32, TOWER / 32), 256, 0, stream>>>(
        W_bt, BULK, TOWER, Wbt_h, Wbt_l);
    k_conv_transpose<<<dim3(TOWER / 32, BULK / 32), 256, 0, stream>>>(
        W_tb, TOWER, BULK, Wtb_h, Wtb_l);

    // encode GEMM: pre1 = x @ W_bt
    k_gemm_split<true><<<dim3(NROWS / 128, TOWER / 128), 256, 0, stream>>>(
        x, nullptr, nullptr, Wbt_h, Wbt_l, pre1, BULK, TOWER);

    // per-row: LN -> proj8 -> rmsnorm -> E8 RVQ -> decode -> LN -> t2 (hi/lo)
    k_rows<<<NROWS / 4, 256, 0, stream>>>(pre1, b_bt, g_et, be_et, W_t8, b_t8,
                                          rms_g, W_8t, b_8t, g_dt, b_dt, t2h,
                                          t2l);

    // decode GEMM: d_out = t2 @ W_tb (pre-LN)
    k_gemm_split<false><<<dim3(NROWS / 128, BULK / 128), 256, 0, stream>>>(
        nullptr, t2h, t2l, Wtb_h, Wtb_l, out, TOWER, BULK);

    // final LN in place
    k_ln2<<<NROWS, 256, 0, stream>>>(out, b_tb, g_db, b_db);
}

// Round 5
// 469.441 us; speedup vs baseline: 1.2026x; 1.1609x over previous
//
#include <hip/hip_runtime.h>

#define BULK 2048
#define TOWER 512
#define E8D 8
#define NROWS 16384
#define LO_SCALE 2048.0f
#define LO_INV (1.0f / 2048.0f)

typedef _Float16 f16x8 __attribute__((ext_vector_type(8)));
typedef float f32x4 __attribute__((ext_vector_type(4)));

// async global->LDS, 16B per lane, dest = wave-uniform base + lane*16
#define GLOAD(g, l)                                                        \
    __builtin_amdgcn_global_load_lds(                                      \
        (const __attribute__((address_space(1))) void*)(g),                \
        (__attribute__((address_space(3))) void*)(l), 16, 0, 0)

// ---------------------------------------------------------------------------
// Weight prep: fp32 [K][N] -> transposed fp16 [N][K]; optionally lo residual
// (scaled by 2^11) for the split path.
// ---------------------------------------------------------------------------
template <bool LO>
__global__ void k_conv_transpose(const float* __restrict__ in, int K, int N,
                                 _Float16* __restrict__ out_hi,
                                 _Float16* __restrict__ out_lo) {
    __shared__ float tile[32][33];
    int tx = threadIdx.x & 31, ty = threadIdx.x >> 5;  // 32 x 8
    int k0 = blockIdx.x * 32, n0 = blockIdx.y * 32;
#pragma unroll
    for (int i = 0; i < 32; i += 8)
        tile[ty + i][tx] = in[(size_t)(k0 + ty + i) * N + (n0 + tx)];
    __syncthreads();
#pragma unroll
    for (int i = 0; i < 32; i += 8) {
        int n = n0 + ty + i, k = k0 + tx;
        float v = tile[tx][ty + i];
        _Float16 h = (_Float16)v;
        out_hi[(size_t)n * K + k] = h;
        if constexpr (LO)
            out_lo[(size_t)n * K + k] = (_Float16)((v - (float)h) * LO_SCALE);
    }
}

// ---------------------------------------------------------------------------
// GEMM, double-buffered single-barrier K-loop, 128x128 tile, BK=32, 4 waves.
// MODE 0: A fp32 (reg-staged, split hi/lo in-kernel), B hi/lo fp16 [N][K],
//         3 MFMA passes (hh + hl + lh). Error ~2^-22 — quantizer-safe.
// MODE 1: A fp16 [M][K], B fp16 [N][K], 1 MFMA pass. Error ~4e-4 relative —
//         fine for the decode GEMM (feeds LayerNorm only).
// ---------------------------------------------------------------------------
template <int MODE>
__global__ __launch_bounds__(256, 2) void k_gemm_split(
    const float* __restrict__ Af, const _Float16* __restrict__ Ah,
    const _Float16* __restrict__ Bh, const _Float16* __restrict__ Bl,
    float* __restrict__ C, int K, int N) {
    constexpr int NOPS = (MODE == 0) ? 4 : 2;
    __shared__ _Float16 lds[2][NOPS][128][32];  // 64 KB / 32 KB
    const int t = threadIdx.x;
    const int m0 = blockIdx.x * 128, n0 = blockIdx.y * 128;
    const int wid = t >> 6, lane = t & 63;
    const int wr = wid >> 1, wc = wid & 1;
    const int lr = lane & 15, kg = lane >> 4;

    f32x4 acc1[4][4] = {};
    f32x4 acc2[4][4] = {};  // unused in MODE 1 (DCE'd)

    // ---- staging geometry ----
    const int sr = t >> 1, sc = (t & 1) * 16;  // MODE0 A: 16 floats/thread
    const float* aptr = nullptr;
    const _Float16 *bhp = nullptr, *blp = nullptr, *gp = nullptr;
    float areg[16];
    const int c0 = wid * 2;

    if constexpr (MODE == 0) {
        aptr = Af + (size_t)(m0 + sr) * K + sc;
        // B gload: wave w stages chunks {2w,2w+1} of Bh and Bl.
        bhp = Bh + (size_t)(n0 + c0 * 16 + (lane >> 2)) * K + (lane & 3) * 8;
        blp = Bl + (size_t)(n0 + c0 * 16 + (lane >> 2)) * K + (lane & 3) * 8;
    } else {
        // wave w stages operand w>>1 (0=A,1=B), rows (w&1)*64 .. +64
        const _Float16* gop = (wid >> 1) ? Bh : Ah;
        const int r0 = ((wid >> 1) ? n0 : m0) + (wid & 1) * 64 + (lane >> 2);
        gp = gop + (size_t)r0 * K + (lane & 3) * 8;
    }

    auto loadA = [&](int k0) {
        const float* p = aptr + k0;
        *(float4*)&areg[0] = *(const float4*)(p);
        *(float4*)&areg[4] = *(const float4*)(p + 4);
        *(float4*)&areg[8] = *(const float4*)(p + 8);
        *(float4*)&areg[12] = *(const float4*)(p + 12);
    };
    auto stageB = [&](int k0, int bb) {
        GLOAD(bhp + k0, &lds[bb][2][c0 * 16][0]);
        GLOAD(bhp + k0 + (size_t)16 * K, &lds[bb][2][c0 * 16 + 16][0]);
        GLOAD(blp + k0, &lds[bb][3][c0 * 16][0]);
        GLOAD(blp + k0 + (size_t)16 * K, &lds[bb][3][c0 * 16 + 16][0]);
    };
    auto writeA = [&](int bb) {
        f16x8 hv0, hv1, lv0, lv1;
#pragma unroll
        for (int e = 0; e < 8; ++e) {
            float va = areg[e], vb = areg[8 + e];
            _Float16 ha = (_Float16)va, hb = (_Float16)vb;
            hv0[e] = ha;
            hv1[e] = hb;
            lv0[e] = (_Float16)((va - (float)ha) * LO_SCALE);
            lv1[e] = (_Float16)((vb - (float)hb) * LO_SCALE);
        }
        *(f16x8*)&lds[bb][0][sr][sc] = hv0;
        *(f16x8*)&lds[bb][0][sr][sc + 8] = hv1;
        *(f16x8*)&lds[bb][1][sr][sc] = lv0;
        *(f16x8*)&lds[bb][1][sr][sc + 8] = lv1;
    };
    auto stageAll = [&](int k0, int bb) {  // MODE 1: 4 GLOADs per wave
#pragma unroll
        for (int j = 0; j < 4; ++j)
            GLOAD(gp + k0 + (size_t)(j * 16) * K,
                  &lds[bb][wid >> 1][(wid & 1) * 64 + j * 16][0]);
    };

    // ---- prologue: stage tile 0 into buf 0 ----
    if constexpr (MODE == 0) {
        loadA(0);
        stageB(0, 0);
        writeA(0);
    } else {
        stageAll(0, 0);
    }
    __syncthreads();

    const int nk = K / 32;
    for (int kt = 0; kt < nk; ++kt) {
        const int b = kt & 1;
        // issue next tile's loads before computing (overlap under MFMAs)
        if (kt + 1 < nk) {
            if constexpr (MODE == 0) {
                loadA((kt + 1) * 32);
                stageB((kt + 1) * 32, b ^ 1);
            } else {
                stageAll((kt + 1) * 32, b ^ 1);
            }
        }

        if constexpr (MODE == 0) {
            f16x8 a_h[4], a_l[4], b_h[4], b_l[4];
#pragma unroll
            for (int m = 0; m < 4; ++m) {
                int r = wr * 64 + m * 16 + lr;
                a_h[m] = *(const f16x8*)&lds[b][0][r][kg * 8];
                a_l[m] = *(const f16x8*)&lds[b][1][r][kg * 8];
            }
#pragma unroll
            for (int n = 0; n < 4; ++n) {
                int r = wc * 64 + n * 16 + lr;
                b_h[n] = *(const f16x8*)&lds[b][2][r][kg * 8];
                b_l[n] = *(const f16x8*)&lds[b][3][r][kg * 8];
            }
#pragma unroll
            for (int m = 0; m < 4; ++m)
#pragma unroll
                for (int n = 0; n < 4; ++n) {
                    acc1[m][n] = __builtin_amdgcn_mfma_f32_16x16x32_f16(
                        a_h[m], b_h[n], acc1[m][n], 0, 0, 0);
                    acc2[m][n] = __builtin_amdgcn_mfma_f32_16x16x32_f16(
                        a_h[m], b_l[n], acc2[m][n], 0, 0, 0);
                    acc2[m][n] = __builtin_amdgcn_mfma_f32_16x16x32_f16(
                        a_l[m], b_h[n], acc2[m][n], 0, 0, 0);
                }
            // A conversion after MFMAs; writes target buf b^1.
            if (kt + 1 < nk) writeA(b ^ 1);
        } else {
            f16x8 a_h[4], b_h[4];
#pragma unroll
            for (int m = 0; m < 4; ++m) {
                int r = wr * 64 + m * 16 + lr;
                a_h[m] = *(const f16x8*)&lds[b][0][r][kg * 8];
            }
#pragma unroll
            for (int n = 0; n < 4; ++n) {
                int r = wc * 64 + n * 16 + lr;
                b_h[n] = *(const f16x8*)&lds[b][1][r][kg * 8];
            }
#pragma unroll
            for (int m = 0; m < 4; ++m)
#pragma unroll
                for (int n = 0; n < 4; ++n)
                    acc1[m][n] = __builtin_amdgcn_mfma_f32_16x16x32_f16(
                        a_h[m], b_h[n], acc1[m][n], 0, 0, 0);
        }
        __syncthreads();  // drains vmcnt(0)+lgkmcnt(0): next buf ready
    }

    // epilogue
#pragma unroll
    for (int m = 0; m < 4; ++m)
#pragma unroll
        for (int n = 0; n < 4; ++n)
#pragma unroll
            for (int i = 0; i < 4; ++i) {
                int row = m0 + wr * 64 + m * 16 + kg * 4 + i;
                int col = n0 + wc * 64 + n * 16 + lr;
                float v = acc1[m][n][i];
                if constexpr (MODE == 0) v += acc2[m][n][i] * LO_INV;
                C[(size_t)row * N + col] = v;
            }
}

// ---------------------------------------------------------------------------
// E8 lattice quantizer (faithful to the reference, fp32 scalar per lane)
// ---------------------------------------------------------------------------
__device__ inline void nearest_d8(const float* x, float* f) {
    float s = 0.f;
#pragma unroll
    for (int j = 0; j < 8; ++j) {
        f[j] = rintf(x[j]);  // round-half-even == jnp.round
        s += f[j];
    }
    float besta = -1.f, beste = 0.f;
    int bidx = 0;
#pragma unroll
    for (int j = 0; j < 8; ++j) {
        float e = x[j] - f[j];
        float a = fabsf(e);
        if (a > besta) { besta = a; beste = e; bidx = j; }  // first max kept
    }
    if (fmodf(s, 2.0f) != 0.0f) {
        float adj = (beste >= 0.f) ? 1.f : -1.f;
#pragma unroll
        for (int j = 0; j < 8; ++j) f[j] += (j == bidx) ? adj : 0.f;
    }
}

__device__ inline void nearest_e8(const float* x, float* out) {
    float fa[8], xs[8], fb[8];
    nearest_d8(x, fa);
#pragma unroll
    for (int j = 0; j < 8; ++j) xs[j] = x[j] - 0.5f;
    nearest_d8(xs, fb);
#pragma unroll
    for (int j = 0; j < 8; ++j) fb[j] += 0.5f;
    float da = 0.f, db = 0.f;
#pragma unroll
    for (int j = 0; j < 8; ++j) {
        float ea = x[j] - fa[j], eb = x[j] - fb[j];
        da += ea * ea;
        db += eb * eb;
    }
    bool pa = (da <= db);
#pragma unroll
    for (int j = 0; j < 8; ++j) out[j] = pa ? fa[j] : fb[j];
}

__device__ inline float wred64(float v) {
#pragma unroll
    for (int off = 1; off < 64; off <<= 1) v += __shfl_xor(v, off, 64);
    return v;
}

// ---------------------------------------------------------------------------
// Stage A of the middle section: LN(512) -> proj 512->8 -> rmsnorm -> e8.
// One wave per row; lane 0 writes the 8-vector.
// ---------------------------------------------------------------------------
__global__ __launch_bounds__(256) void k_rows_a(
    const float* __restrict__ pre1, const float* __restrict__ b_bt,
    const float* __restrict__ g_et, const float* __restrict__ be_et,
    const float* __restrict__ W_t8, const float* __restrict__ b_t8,
    const float* __restrict__ rms_g, float* __restrict__ e8buf) {
    int wid = threadIdx.x >> 6, lane = threadIdx.x & 63;
    int row = blockIdx.x * 4 + wid;
    int cb = lane * 8;

    const float* src = pre1 + (size_t)row * TOWER + cb;
    float v[8];
    *(float4*)&v[0] = *(const float4*)(src);
    *(float4*)&v[4] = *(const float4*)(src + 4);
#pragma unroll
    for (int i = 0; i < 8; ++i) v[i] += b_bt[cb + i];

    float s = 0.f;
#pragma unroll
    for (int i = 0; i < 8; ++i) s += v[i];
    s = wred64(s);
    float mu = s * (1.f / 512.f);
    float ss = 0.f;
#pragma unroll
    for (int i = 0; i < 8; ++i) { float d = v[i] - mu; ss += d * d; }
    ss = wred64(ss);
    float inv = 1.f / sqrtf(ss * (1.f / 512.f) + 1e-6f);
    float tw[8];
#pragma unroll
    for (int i = 0; i < 8; ++i)
        tw[i] = (v[i] - mu) * inv * g_et[cb + i] + be_et[cb + i];

    float p[8] = {0.f, 0.f, 0.f, 0.f, 0.f, 0.f, 0.f, 0.f};
#pragma unroll
    for (int i = 0; i < 8; ++i) {
        const float* wr_ = W_t8 + (size_t)(cb + i) * 8;
#pragma unroll
        for (int j = 0; j < 8; ++j) p[j] += tw[i] * wr_[j];
    }
#pragma unroll
    for (int j = 0; j < 8; ++j) p[j] = wred64(p[j]);

    float e8[8];
    float ms = 0.f;
#pragma unroll
    for (int j = 0; j < 8; ++j) {
        e8[j] = p[j] + b_t8[j];
        ms += e8[j] * e8[j];
    }
    float rms = sqrtf(ms * (1.f / 8.f) + 1e-6f);
#pragma unroll
    for (int j = 0; j < 8; ++j) e8[j] = e8[j] / rms * rms_g[j];

    if (lane == 0) {
        float4 f0 = {e8[0], e8[1], e8[2], e8[3]};
        float4 f1 = {e8[4], e8[5], e8[6], e8[7]};
        *(float4*)(e8buf + (size_t)row * 8) = f0;
        *(float4*)(e8buf + (size_t)row * 8 + 4) = f1;
    }
}

// ---------------------------------------------------------------------------
// Row-per-lane residual E8 quantize (removes the 64x per-lane redundancy).
// ---------------------------------------------------------------------------
__global__ __launch_bounds__(256) void k_quant(const float* __restrict__ e8buf,
                                               float* __restrict__ qbuf) {
    int row = blockIdx.x * 256 + threadIdx.x;
    float r[8];
    *(float4*)&r[0] = *(const float4*)(e8buf + (size_t)row * 8);
    *(float4*)&r[4] = *(const float4*)(e8buf + (size_t)row * 8 + 4);
    float q[8] = {0.f, 0.f, 0.f, 0.f, 0.f, 0.f, 0.f, 0.f};
#pragma unroll
    for (int lvl = 0; lvl < 8; ++lvl) {
        float ql[8];
        nearest_e8(r, ql);
#pragma unroll
        for (int j = 0; j < 8; ++j) { q[j] += ql[j]; r[j] -= ql[j]; }
    }
    float4 f0 = {q[0], q[1], q[2], q[3]};
    float4 f1 = {q[4], q[5], q[6], q[7]};
    *(float4*)(qbuf + (size_t)row * 8) = f0;
    *(float4*)(qbuf + (size_t)row * 8 + 4) = f1;
}

// ---------------------------------------------------------------------------
// Stage B: decode 8 -> 512, LN, emit t2 as fp16 (single precision level —
// GEMM2 runs hh-only). One wave per row.
// ---------------------------------------------------------------------------
__global__ __launch_bounds__(256) void k_rows_b(
    const float* __restrict__ qbuf, const float* __restrict__ W_8t,
    const float* __restrict__ b_8t, const float* __restrict__ g_dt,
    const float* __restrict__ b_dt, _Float16* __restrict__ t2h) {
    int wid = threadIdx.x >> 6, lane = threadIdx.x & 63;
    int row = blockIdx.x * 4 + wid;
    int cb = lane * 8;

    float q[8];
    *(float4*)&q[0] = *(const float4*)(qbuf + (size_t)row * 8);      // bcast
    *(float4*)&q[4] = *(const float4*)(qbuf + (size_t)row * 8 + 4);

    float o[8];
#pragma unroll
    for (int i = 0; i < 8; ++i) {
        int c = cb + i;
        float acc = b_8t[c];
#pragma unroll
        for (int j = 0; j < 8; ++j) acc += q[j] * W_8t[(size_t)j * TOWER + c];
        o[i] = acc;
    }
    float s2 = 0.f;
#pragma unroll
    for (int i = 0; i < 8; ++i) s2 += o[i];
    s2 = wred64(s2);
    float mu2 = s2 * (1.f / 512.f);
    float ss2 = 0.f;
#pragma unroll
    for (int i = 0; i < 8; ++i) { float d = o[i] - mu2; ss2 += d * d; }
    ss2 = wred64(ss2);
    float inv2 = 1.f / sqrtf(ss2 * (1.f / 512.f) + 1e-6f);

    f16x8 hv;
#pragma unroll
    for (int i = 0; i < 8; ++i) {
        int c = cb + i;
        float t2v = (o[i] - mu2) * inv2 * g_dt[c] + b_dt[c];
        hv[i] = (_Float16)t2v;
    }
    *(f16x8*)(t2h + (size_t)row * TOWER + cb) = hv;
}

// ---------------------------------------------------------------------------
// Final LN over 2048, in place on d_out (which holds t2 @ W_tb).
// ---------------------------------------------------------------------------
__global__ __launch_bounds__(256) void k_ln2(float* __restrict__ out,
                                             const float* __restrict__ b_tb,
                                             const float* __restrict__ g,
                                             const float* __restrict__ b) {
    __shared__ float red[4];
    int t = threadIdx.x, wid = t >> 6, lane = t & 63;
    size_t base = (size_t)blockIdx.x * BULK;
    int cb = t * 8;
    float v[8];
    *(float4*)&v[0] = *(const float4*)(out + base + cb);
    *(float4*)&v[4] = *(const float4*)(out + base + cb + 4);
#pragma unroll
    for (int i = 0; i < 8; ++i) v[i] += b_tb[cb + i];

    float s = 0.f;
#pragma unroll
    for (int i = 0; i < 8; ++i) s += v[i];
    s = wred64(s);
    if (lane == 0) red[wid] = s;
    __syncthreads();
    float tot = red[0] + red[1] + red[2] + red[3];
    float mu = tot * (1.f / 2048.f);
    __syncthreads();
    float ss = 0.f;
#pragma unroll
    for (int i = 0; i < 8; ++i) { float d = v[i] - mu; ss += d * d; }
    ss = wred64(ss);
    if (lane == 0) red[wid] = ss;
    __syncthreads();
    float vtot = red[0] + red[1] + red[2] + red[3];
    float inv = 1.f / sqrtf(vtot * (1.f / 2048.f) + 1e-6f);
#pragma unroll
    for (int i = 0; i < 8; ++i) v[i] = (v[i] - mu) * inv * g[cb + i] + b[cb + i];
    *(float4*)(out + base + cb) = *(float4*)&v[0];
    *(float4*)(out + base + cb + 4) = *(float4*)&v[4];
}

// ---------------------------------------------------------------------------
extern "C" void kernel_launch(void* const* d_in, const int* in_sizes, int n_in,
                              void* d_out, int out_size, void* d_ws,
                              size_t ws_size, hipStream_t stream) {
    const float* x     = (const float*)d_in[0];
    const float* W_bt  = (const float*)d_in[1];
    const float* b_bt  = (const float*)d_in[2];
    const float* g_et  = (const float*)d_in[3];
    const float* be_et = (const float*)d_in[4];
    const float* W_t8  = (const float*)d_in[5];
    const float* b_t8  = (const float*)d_in[6];
    const float* rms_g = (const float*)d_in[7];
    const float* W_8t  = (const float*)d_in[8];
    const float* b_8t  = (const float*)d_in[9];
    const float* g_dt  = (const float*)d_in[10];
    const float* b_dt  = (const float*)d_in[11];
    const float* W_tb  = (const float*)d_in[12];
    const float* b_tb  = (const float*)d_in[13];
    const float* g_db  = (const float*)d_in[14];
    const float* b_db  = (const float*)d_in[15];
    float* out = (float*)d_out;

    // Workspace (23 MB)
    char* w = (char*)d_ws;
    _Float16* Wbt_h = (_Float16*)w; w += (size_t)BULK * TOWER * 2;
    _Float16* Wbt_l = (_Float16*)w; w += (size_t)BULK * TOWER * 2;
    _Float16* Wtb_h = (_Float16*)w; w += (size_t)TOWER * BULK * 2;
    _Float16* t2h   = (_Float16*)w; w += (size_t)NROWS * TOWER * 2;
    float*    e8buf = (float*)w;    w += (size_t)NROWS * E8D * 4;
    float*    qbuf  = (float*)w;    w += (size_t)NROWS * E8D * 4;
    // pre1 (32 MB) lives in d_out (128 MB); fully overwritten by GEMM2 later.
    float* pre1 = out;

    // weight prep
    k_conv_transpose<true><<<dim3(BULK / 32, TOWER / 32), 256, 0, stream>>>(
        W_bt, BULK, TOWER, Wbt_h, Wbt_l);
    k_conv_transpose<false><<<dim3(TOWER / 32, BULK / 32), 256, 0, stream>>>(
        W_tb, TOWER, BULK, Wtb_h, nullptr);

    // encode GEMM (3-pass split fp16, quantizer-safe): pre1 = x @ W_bt
    k_gemm_split<0><<<dim3(NROWS / 128, TOWER / 128), 256, 0, stream>>>(
        x, nullptr, Wbt_h, Wbt_l, pre1, BULK, TOWER);

    // middle: LN+proj+rms -> e8 ; row-per-lane RVQ ; decode+LN -> t2 fp16
    k_rows_a<<<NROWS / 4, 256, 0, stream>>>(pre1, b_bt, g_et, be_et, W_t8,
                                            b_t8, rms_g, e8buf);
    k_quant<<<NROWS / 256, 256, 0, stream>>>(e8buf, qbuf);
    k_rows_b<<<NROWS / 4, 256, 0, stream>>>(qbuf, W_8t, b_8t, g_dt, b_dt, t2h);

    // decode GEMM (single-pass fp16): d_out = t2 @ W_tb (pre-LN)
    k_gemm_split<1><<<dim3(NROWS / 128, BULK / 128), 256, 0, stream>>>(
        nullptr, t2h, Wtb_h, nullptr, out, TOWER, BULK);

    // final LN in place
    k_ln2<<<NROWS, 256, 0, stream>>>(out, b_tb, g_db, b_db);
}